// Round 2
// baseline (217.434 us; speedup 1.0000x reference)
//
#include <hip/hip_runtime.h>
#include <math.h>

#define N_BATCH 8
#define IN_CH   256
#define OUT_CH  256
#define T_LEN   2048
#define DKS     33
#define PAD     16
#define KC      16

// conv tiling
#define MT 64      // out-channels per block
#define TT 128     // time per block
#define XS_STRIDE 40           // Xs row stride in bf16 elements (80B, 16B-aligned)
#define XS_ELEMS (160 * XS_STRIDE)

typedef __attribute__((ext_vector_type(8))) short bf16x8;
typedef __attribute__((ext_vector_type(4))) float f32x4;

__device__ __forceinline__ unsigned short f2bf(float f) {
    unsigned u = __builtin_bit_cast(unsigned, f);
    unsigned r = (u + 0x7FFFu + ((u >> 16) & 1u)) >> 16;   // RNE
    return (unsigned short)r;
}

// ---------------------------------------------------------------------------
// Kernel 1: construct dense conv kernel in bf16, fragment-ready layout:
//   element (o,i,d) lives at
//   ((g*8 + c)*33 + d)*2048 + a*512 + l*8 + j
//   where g=o>>6, a=(o>>4)&3, m=o&15, c=i>>5, i_local=i&31,
//         quad=i_local>>3, j=i_local&7, l=quad*16+m.
// GATHER formulation (no runtime-indexed array -> no scratch).
// Faithful reference semantics: frac from out-channel 0; second tap dropped
// when p1+1 == 33 (d-1 <= 31 never matches).
// ---------------------------------------------------------------------------
__global__ void build_kern(const float* __restrict__ weight,
                           const float* __restrict__ P,
                           unsigned short* __restrict__ kern_f) {
    int idx = blockIdx.x * blockDim.x + threadIdx.x;   // o*IN_CH + i
    if (idx >= OUT_CH * IN_CH) return;
    int o = idx / IN_CH;
    int i = idx % IN_CH;

    const float* Po = P      + (size_t)(o * IN_CH + i) * KC;
    const float* P0 = P      + (size_t)i * KC;           // out-channel 0
    const float* Wo = weight + (size_t)(o * IN_CH + i) * KC;

    int   p1[KC];
    float w1[KC], w2[KC];
#pragma unroll
    for (int k = 0; k < KC; ++k) {
        float pp = Po[k] + (float)(DKS / 2);
        float p0 = P0[k] + (float)(DKS / 2);
        float fr = p0 - floorf(p0);
        float w  = Wo[k];
        p1[k] = (int)floorf(pp);
        w1[k] = w * (1.0f - fr);
        w2[k] = w * fr;
    }

    int g  = o >> 6;
    int ai = (o >> 4) & 3;
    int m  = o & 15;
    int c  = i >> 5;
    int il = i & 31;
    int q  = il >> 3;
    int j  = il & 7;
    size_t base = ((size_t)(g * 8 + c) * 33) * 2048
                + (size_t)ai * 512 + (size_t)(q * 16 + m) * 8 + j;

#pragma unroll
    for (int d = 0; d < DKS; ++d) {
        float acc = 0.0f;
#pragma unroll
        for (int k = 0; k < KC; ++k) {
            acc += (p1[k] == d)     ? w1[k] : 0.0f;
            acc += (p1[k] == d - 1) ? w2[k] : 0.0f;
        }
        kern_f[base + (size_t)d * 2048] = f2bf(acc);
    }
}

// ---------------------------------------------------------------------------
// Kernel 2: implicit-GEMM conv with MFMA 16x16x32 bf16.
// Block: 256 thr = 4 waves in a 2x2 grid. Block tile 64o x 128t;
// wave tile 32o x 64t  (A-side redundancy 2x instead of 4x -> halves kern
// L2 traffic vs the 64o x 32t split).
// K-loop: 8 i-chunks of 32; inner d-loop of 33, barrier-free, software-
// pipelined 2-deep (3-stage rotating A/B register buffers).
// Xs double-buffered: chunk c+1's global loads issued BEFORE the d-loop,
// LDS writes after it (T14 split) -> 1 barrier per chunk.
// ---------------------------------------------------------------------------
#define STAGE_LOAD(CH)                                                        \
    {                                                                         \
        const int i0_ = (CH) * 32;                                            \
        _Pragma("unroll")                                                     \
        for (int it = 0; it < 10; ++it) {                                     \
            int idx = tid + it * 256;          /* 0..2559 */                  \
            int ip  = idx / 160;               /* i-pair 0..15 */             \
            int t   = idx - ip * 160;          /* 0..159 */                   \
            int gg  = t0 - PAD + t;                                           \
            float v0 = 0.f, v1 = 0.f;                                         \
            if ((unsigned)gg < (unsigned)T_LEN) {                             \
                const float* xb = x + ((size_t)(batch * IN_CH + i0_ + ip * 2) * T_LEN) + gg; \
                v0 = xb[0];                                                   \
                v1 = xb[T_LEN];                                               \
            }                                                                 \
            sv0[it] = v0; sv1[it] = v1;                                       \
        }                                                                     \
    }

#define STAGE_WRITE(BUF)                                                      \
    {                                                                         \
        _Pragma("unroll")                                                     \
        for (int it = 0; it < 10; ++it) {                                     \
            int idx = tid + it * 256;                                         \
            int ip  = idx / 160;                                              \
            int t   = idx - ip * 160;                                         \
            unsigned pk = (unsigned)f2bf(sv0[it]) | ((unsigned)f2bf(sv1[it]) << 16); \
            *(unsigned*)(&Xs[BUF][t * XS_STRIDE + ip * 2]) = pk;              \
        }                                                                     \
    }

#define AFL(BUF, D)                                                           \
    {                                                                         \
        BUF[0] = *(const bf16x8*)(kfb + (size_t)(D) * 2048);                  \
        BUF[1] = *(const bf16x8*)(kfb + (size_t)(D) * 2048 + 512);            \
    }

#define BFL(BUF, D)                                                           \
    {                                                                         \
        _Pragma("unroll")                                                     \
        for (int bb = 0; bb < 4; ++bb)                                        \
            BUF[bb] = *(const bf16x8*)(&Xs[cur][(wt2 + bb * 16 + lm + (D)) * XS_STRIDE + quad * 8]); \
    }

#define MM(AB, BB)                                                            \
    {                                                                         \
        _Pragma("unroll")                                                     \
        for (int aa = 0; aa < 2; ++aa)                                        \
            _Pragma("unroll")                                                 \
            for (int bb = 0; bb < 4; ++bb)                                    \
                acc[aa][bb] = __builtin_amdgcn_mfma_f32_16x16x32_bf16(        \
                    AB[aa], BB[bb], acc[aa][bb], 0, 0, 0);                    \
    }

__global__ __launch_bounds__(256, 2) void dcls_conv(
    const float* __restrict__ x,
    const unsigned short* __restrict__ kern_f,
    const float* __restrict__ bias,
    float* __restrict__ out)
{
    __shared__ unsigned short Xs[2][XS_ELEMS];   // 2 x 12.8KB

    const int t0    = blockIdx.x * TT;
    const int o0    = blockIdx.y * MT;
    const int batch = blockIdx.z;

    const int tid  = threadIdx.x;
    const int w    = tid >> 6;        // wave id 0..3
    const int l    = tid & 63;
    const int quad = l >> 4;
    const int lm   = l & 15;
    const int wo   = w >> 1;          // o-half (0..1): a-frags wo*2, wo*2+1
    const int wt2  = (w & 1) * 64;    // t-base within block tile (0 or 64)

    f32x4 acc[2][4];
#pragma unroll
    for (int aa = 0; aa < 2; ++aa)
#pragma unroll
        for (int bb = 0; bb < 4; ++bb) acc[aa][bb] = (f32x4){0.f, 0.f, 0.f, 0.f};

    float sv0[10], sv1[10];

    // prologue: stage chunk 0
    STAGE_LOAD(0);
    STAGE_WRITE(0);
    __syncthreads();

    for (int c = 0; c < 8; ++c) {
        const int cur = c & 1;

        // issue chunk c+1's global loads now; latency hides under 264 MFMAs
        if (c < 7) STAGE_LOAD(c + 1);

        const unsigned short* kfb = kern_f
            + ((size_t)(blockIdx.y * 8 + c) * 33) * 2048
            + (size_t)(wo * 1024) + (size_t)l * 8;

        // ---- 33 barrier-free K-steps over d, 3-stage rotating pipeline ----
        bf16x8 A0[2], A1[2], A2[2];
        bf16x8 B0[4], B1[4], B2[4];
        AFL(A0, 0); BFL(B0, 0);
        AFL(A1, 1); BFL(B1, 1);
        for (int k = 0; k < 10; ++k) {
            const int d = 3 * k;
            AFL(A2, d + 2); BFL(B2, d + 2);
            MM(A0, B0);                       // compute d
            AFL(A0, d + 3); BFL(B0, d + 3);
            MM(A1, B1);                       // compute d+1
            AFL(A1, d + 4); BFL(B1, d + 4);
            MM(A2, B2);                       // compute d+2
        }
        // tail: d = 30, 31, 32
        AFL(A2, 32); BFL(B2, 32);
        MM(A0, B0);
        MM(A1, B1);
        MM(A2, B2);

        // write chunk c+1 into the other buffer, then one barrier
        if (c < 7) STAGE_WRITE(cur ^ 1);
        __syncthreads();
    }

    // ---- epilogue: bias + fp32 stores ----
#pragma unroll
    for (int aa = 0; aa < 2; ++aa) {
#pragma unroll
        for (int r = 0; r < 4; ++r) {
            int o = o0 + (wo * 2 + aa) * 16 + quad * 4 + r;
            float bv = bias[o];
            float* orow = out + ((size_t)(batch * OUT_CH + o) * T_LEN) + t0 + wt2 + lm;
#pragma unroll
            for (int bb = 0; bb < 4; ++bb)
                orow[bb * 16] = acc[aa][bb][r] + bv;
        }
    }
}

extern "C" void kernel_launch(void* const* d_in, const int* in_sizes, int n_in,
                              void* d_out, int out_size, void* d_ws, size_t ws_size,
                              hipStream_t stream) {
    const float* x      = (const float*)d_in[0];
    const float* weight = (const float*)d_in[1];
    const float* P      = (const float*)d_in[2];
    const float* bias   = (const float*)d_in[3];
    float*       out    = (float*)d_out;
    unsigned short* kern_f = (unsigned short*)d_ws;   // 256*256*33 bf16 = 4.33MB

    hipLaunchKernelGGL(build_kern,
                       dim3((OUT_CH * IN_CH + 255) / 256), dim3(256), 0, stream,
                       weight, P, kern_f);

    dim3 grid(T_LEN / TT, OUT_CH / MT, N_BATCH);
    hipLaunchKernelGGL(dcls_conv, grid, dim3(256), 0, stream,
                       x, kern_f, bias, out);
}

// Round 3
// 175.754 us; speedup vs baseline: 1.2371x; 1.2371x over previous
//
#include <hip/hip_runtime.h>
#include <math.h>

#define N_BATCH 8
#define IN_CH   256
#define OUT_CH  256
#define T_LEN   2048
#define DKS     33
#define PAD     16
#define KC      16

// conv tiling
#define MT 32      // out-channels per block (halved vs r1 -> 2x grid -> 4 blocks/CU)
#define TT 128     // time per block (4 waves x 32)
#define XS_STRIDE 40   // Xs row stride in bf16 elements (80B, 16B-aligned)

typedef __attribute__((ext_vector_type(8))) short bf16x8;
typedef __attribute__((ext_vector_type(4))) float f32x4;

__device__ __forceinline__ unsigned short f2bf(float f) {
    unsigned u = __builtin_bit_cast(unsigned, f);
    unsigned r = (u + 0x7FFFu + ((u >> 16) & 1u)) >> 16;   // RNE
    return (unsigned short)r;
}

// ---------------------------------------------------------------------------
// Kernel 1: construct dense conv kernel in bf16, fragment-ready layout:
//   element (o,i,d) lives at
//   ((g*8 + c)*33 + d)*2048 + a*512 + l*8 + j
//   where g=o>>6, a=(o>>4)&3, m=o&15, c=i>>5, i_local=i&31,
//         quad=i_local>>3, j=i_local&7, l=quad*16+m.
// GATHER formulation (no runtime-indexed array -> no scratch).
// Faithful reference semantics: frac from out-channel 0; second tap dropped
// when p1+1 == 33 (d-1 <= 31 never matches).
// ---------------------------------------------------------------------------
__global__ void build_kern(const float* __restrict__ weight,
                           const float* __restrict__ P,
                           unsigned short* __restrict__ kern_f) {
    int idx = blockIdx.x * blockDim.x + threadIdx.x;   // o*IN_CH + i
    if (idx >= OUT_CH * IN_CH) return;
    int o = idx / IN_CH;
    int i = idx % IN_CH;

    const float* Po = P      + (size_t)(o * IN_CH + i) * KC;
    const float* P0 = P      + (size_t)i * KC;           // out-channel 0
    const float* Wo = weight + (size_t)(o * IN_CH + i) * KC;

    int   p1[KC];
    float w1[KC], w2[KC];
#pragma unroll
    for (int k = 0; k < KC; ++k) {
        float pp = Po[k] + (float)(DKS / 2);
        float p0 = P0[k] + (float)(DKS / 2);
        float fr = p0 - floorf(p0);
        float w  = Wo[k];
        p1[k] = (int)floorf(pp);
        w1[k] = w * (1.0f - fr);
        w2[k] = w * fr;
    }

    int g  = o >> 6;
    int ai = (o >> 4) & 3;
    int m  = o & 15;
    int c  = i >> 5;
    int il = i & 31;
    int q  = il >> 3;
    int j  = il & 7;
    size_t base = ((size_t)(g * 8 + c) * 33) * 2048
                + (size_t)ai * 512 + (size_t)(q * 16 + m) * 8 + j;

#pragma unroll
    for (int d = 0; d < DKS; ++d) {
        float acc = 0.0f;
#pragma unroll
        for (int k = 0; k < KC; ++k) {
            acc += (p1[k] == d)     ? w1[k] : 0.0f;
            acc += (p1[k] == d - 1) ? w2[k] : 0.0f;
        }
        kern_f[base + (size_t)d * 2048] = f2bf(acc);
    }
}

// ---------------------------------------------------------------------------
// Kernel 2: implicit-GEMM conv with MFMA 16x16x32 bf16.
// Block: 256 thr = 4 waves. Block tile 32o x 128t; wave tile 32o x 32t.
// Grid 16 x 8 x 8 = 1024 blocks -> 4 blocks/CU -> 4 waves/SIMD (the r1
// structure was grid-limited to 2 waves/SIMD; this is the occupancy fix).
// K-loop: 8 i-chunks of 32; inner d-loop of 33 (barrier-free), compiler-
// scheduled (explicit SW pipelining measurably hurts here - r2 post-mortem).
// A-frags straight from global (L1-hot, shared by all 4 waves).
// B from LDS Xs[t][i] (bf16, transposed during staging). Stride-40 frag
// reads are bank-uniform (starts 4*((5*lm+quad) mod 8)).
// ---------------------------------------------------------------------------
__global__ __launch_bounds__(256, 4) void dcls_conv(
    const float* __restrict__ x,
    const unsigned short* __restrict__ kern_f,
    const float* __restrict__ bias,
    float* __restrict__ out)
{
    __shared__ unsigned short Xs[(TT + 2 * PAD) * XS_STRIDE];  // 160*40*2B = 12.8KB

    const int t0    = blockIdx.x * TT;
    const int o0    = blockIdx.y * MT;
    const int batch = blockIdx.z;

    const int tid  = threadIdx.x;
    const int w    = tid >> 6;        // wave id 0..3
    const int l    = tid & 63;
    const int quad = l >> 4;
    const int lm   = l & 15;
    const int wt   = w * 32;          // wave's t base (local)

    f32x4 acc[2][2];
#pragma unroll
    for (int a = 0; a < 2; ++a)
#pragma unroll
        for (int b = 0; b < 2; ++b) acc[a][b] = (f32x4){0.f, 0.f, 0.f, 0.f};

    // kern base for this block's 32-o slice: g = by>>1, ai base = (by&1)*2
    const size_t kf_ai = (size_t)(blockIdx.y & 1) * 1024 + (size_t)l * 8;
    const int    kf_g  = blockIdx.y >> 1;

    for (int c = 0; c < 8; ++c) {
        __syncthreads();   // previous chunk's reads done before overwrite

        // ---- stage Xs: 32 i x 160 t, transposed, fp32 -> bf16 (RNE) ----
        const int i0 = c * 32;
#pragma unroll
        for (int it = 0; it < 10; ++it) {
            int idx = tid + it * 256;          // 0..2559
            int ip  = idx / 160;               // i-pair 0..15
            int t   = idx - ip * 160;          // 0..159
            int gg  = t0 - PAD + t;
            float v0 = 0.f, v1 = 0.f;
            if ((unsigned)gg < (unsigned)T_LEN) {
                const float* xb = x + ((size_t)(batch * IN_CH + i0 + ip * 2) * T_LEN) + gg;
                v0 = xb[0];
                v1 = xb[T_LEN];
            }
            unsigned pk = (unsigned)f2bf(v0) | ((unsigned)f2bf(v1) << 16);
            *(unsigned*)(&Xs[t * XS_STRIDE + ip * 2]) = pk;
        }
        __syncthreads();

        // ---- 33 barrier-free K-steps over d ----
        const unsigned short* kf = kern_f
            + ((size_t)(kf_g * 8 + c) * 33) * 2048 + kf_ai;

        for (int d = 0; d < DKS; ++d) {
            bf16x8 af[2];
#pragma unroll
            for (int a = 0; a < 2; ++a)
                af[a] = *(const bf16x8*)(kf + (size_t)d * 2048 + a * 512);
            bf16x8 bf[2];
#pragma unroll
            for (int b = 0; b < 2; ++b)
                bf[b] = *(const bf16x8*)(&Xs[(wt + b * 16 + lm + d) * XS_STRIDE + quad * 8]);
#pragma unroll
            for (int a = 0; a < 2; ++a)
#pragma unroll
                for (int b = 0; b < 2; ++b)
                    acc[a][b] = __builtin_amdgcn_mfma_f32_16x16x32_bf16(
                        af[a], bf[b], acc[a][b], 0, 0, 0);
        }
    }

    // ---- epilogue: bias + fp32 stores ----
#pragma unroll
    for (int a = 0; a < 2; ++a) {
#pragma unroll
        for (int r = 0; r < 4; ++r) {
            int o = o0 + a * 16 + quad * 4 + r;
            float bv = bias[o];
            float* orow = out + ((size_t)(batch * OUT_CH + o) * T_LEN) + t0 + wt + lm;
#pragma unroll
            for (int b = 0; b < 2; ++b)
                orow[b * 16] = acc[a][b][r] + bv;
        }
    }
}

extern "C" void kernel_launch(void* const* d_in, const int* in_sizes, int n_in,
                              void* d_out, int out_size, void* d_ws, size_t ws_size,
                              hipStream_t stream) {
    const float* x      = (const float*)d_in[0];
    const float* weight = (const float*)d_in[1];
    const float* P      = (const float*)d_in[2];
    const float* bias   = (const float*)d_in[3];
    float*       out    = (float*)d_out;
    unsigned short* kern_f = (unsigned short*)d_ws;   // 256*256*33 bf16 = 4.33MB

    hipLaunchKernelGGL(build_kern,
                       dim3((OUT_CH * IN_CH + 255) / 256), dim3(256), 0, stream,
                       weight, P, kern_f);

    dim3 grid(T_LEN / TT, OUT_CH / MT, N_BATCH);
    hipLaunchKernelGGL(dcls_conv, grid, dim3(256), 0, stream,
                       x, kern_f, bias, out);
}